// Round 13
// baseline (341.900 us; speedup 1.0000x reference)
//
#include <hip/hip_runtime.h>
#include <cstdint>
#include <cstddef>

typedef __attribute__((ext_vector_type(8))) _Float16 f16x8;
typedef __attribute__((ext_vector_type(2))) __fp16 h2;
typedef __attribute__((ext_vector_type(16))) float f32x16;

#define LO_SCALE 2048.0f
#define LO_INV   (1.0f / 2048.0f)
// OMEGA/(2*pi): folded into all effective weights/biases so the activation is
// sin(2*pi*acc) = v_fract + v_sin (2 exact HW ops). Wf/bf are NOT scaled.
#define OMEGA_SC 4.774648292756860f

union H8 { f16x8 v; _Float16 h[8]; };
union HU4 { f16x8 v; h2 p[4]; _Float16 h[8]; };

// k-permutation: storage position p holds original index
//   perm(p) = (p>>5)*32 + 16*((p>>4)&1) + 8*((p&7)>>2) + 4*((p>>3)&1) + (p&3)
// chosen so the MFMA C-fragment (row = (r&3)+8*(r>>2)+4h) that a lane holds
// after a layer IS the B-fragment set it needs for the next layer:
//   C reg r of frag nf -> position nf*32 + (r>>3)*16 + h*8 + (r&7)
//   B(ks=2q+s) needs positions q*32 + s*16 + h*8 + j  == frag q, r = 8s+j.
// => x stays in REGISTERS across layers; no LDS, no barriers, no lane swap.
// Applied consistently to A-blob (kab), layer-0 blob/coords (kc/kb), Wf.

// ---------------------------------------------------------------------------
// Fused kernel A+C.
// Blocks [0,768): ka_weff_blob — (OMEGA_SC*Weff) + direct A-fragment blob.
// Blocks [768,1024): kc_small — layer-0 blob + effective biases (both scaled).
// whblob per (tl): [nf(8)][ks(16)][part(2)][lane(64)*8 halves]
// w0blob per t: [nf(8)][part(2)][512 halves]
// beff: [t][k(4)][256] fp32 (scaled), k=0: b0+hb0, k>=1: bh[k-1]+hb[k]
// ---------------------------------------------------------------------------
__global__ __launch_bounds__(256) void kab(
    const float* __restrict__ latents, const float* __restrict__ W0,
    const float* __restrict__ b0, const float* __restrict__ bh,
    const float* __restrict__ HW0, const float* __restrict__ HB,
    const float* __restrict__ Wh, const float* __restrict__ HWh,
    _Float16* __restrict__ w0blob, float* __restrict__ beff,
    _Float16* __restrict__ whblob) {
  __shared__ float lat_t[8192];  // [k][f] : 256 x 32
  int tid = threadIdx.x, bid = blockIdx.x;

  if (bid >= 768) {
    // ---------------- kc_small ----------------
    int id = (bid - 768) * 256 + tid;
    if (id < 32768) {
      int t = id >> 10, rem = id & 1023;
      int r2 = rem & 127, part = r2 >> 6, lane = r2 & 63;
      int nf = rem >> 7;
      int o = nf * 32 + (lane & 31), kc = lane >> 5;
      const float* lat = latents + t * 256;
      H8 outv;
#pragma unroll
      for (int j = 0; j < 8; ++j) outv.h[j] = (_Float16)0.0f;
#pragma unroll
      for (int j = 0; j < 8; ++j) {
        int i = 8 * (j >> 2) + 4 * kc + (j & 3);  // perm position -> orig i
        if (i < 3) {
          const float* row = HW0 + (o * 3 + i) * 256;
          float s = W0[o * 3 + i];
          for (int k = 0; k < 256; k += 4)
            s += row[k] * lat[k] + row[k + 1] * lat[k + 1] +
                 row[k + 2] * lat[k + 2] + row[k + 3] * lat[k + 3];
          s *= OMEGA_SC;
          _Float16 hi = (_Float16)s;
          outv.h[j] = part ? (_Float16)((s - (float)hi) * LO_SCALE) : hi;
        }
      }
      *(f16x8*)(w0blob + (size_t)id * 8) = outv.v;
    } else {
      int v = id - 32768;
      int t = v >> 10, k = (v >> 8) & 3, hm = v & 255;
      float base = (k == 0) ? b0[hm] : bh[(k - 1) * 256 + hm];
      const float* lat = latents + t * 256;
      const float* row = HB + (size_t)(k * 256 + hm) * 256;
      float s = base;
      for (int kk = 0; kk < 256; kk += 4)
        s += row[kk] * lat[kk] + row[kk + 1] * lat[kk + 1] +
             row[kk + 2] * lat[kk + 2] + row[kk + 3] * lat[kk + 3];
      beff[v] = s * OMEGA_SC;
    }
    return;
  }

  // ---------------- ka_weff_blob ----------------
  int h = bid & 1, ks = (bid >> 1) & 15, nf = (bid >> 5) & 7, l = bid >> 8;

  {
    int f = tid >> 3, kb = (tid & 7) * 32;
#pragma unroll
    for (int m = 0; m < 32; m += 4) {
      float4 v = *(const float4*)(latents + f * 256 + kb + m);
      lat_t[(kb + m + 0) * 32 + f] = v.x;
      lat_t[(kb + m + 1) * 32 + f] = v.y;
      lat_t[(kb + m + 2) * 32 + f] = v.z;
      lat_t[(kb + m + 3) * 32 + f] = v.w;
    }
  }
  __syncthreads();

  int oo = tid >> 3, jj = tid & 7;
  int o = nf * 32 + oo;
  // permuted fragment position -> original column index i
  int i = (ks >> 1) * 32 + (ks & 1) * 16 + 8 * (jj >> 2) + 4 * h + (jj & 3);
  int r = o * 256 + i;
  const float* rowp = HWh + ((size_t)l * 65536 + (size_t)r) * 256;

  float acc[32];
#pragma unroll
  for (int f = 0; f < 32; ++f) acc[f] = 0.f;

  float curf[16], nxtf[16];
#pragma unroll
  for (int q = 0; q < 4; ++q)
    *(float4*)(curf + q * 4) = *(const float4*)(rowp + q * 4);

  for (int kc = 0; kc < 16; ++kc) {
    if (kc < 15) {
#pragma unroll
      for (int q = 0; q < 4; ++q)
        *(float4*)(nxtf + q * 4) = *(const float4*)(rowp + (kc + 1) * 16 + q * 4);
    }
    const float* lp = lat_t + kc * 512;
#pragma unroll
    for (int m = 0; m < 16; ++m) {
      float hw = curf[m];
#pragma unroll
      for (int fq = 0; fq < 8; ++fq) {
        float4 lv = *(const float4*)(lp + m * 32 + fq * 4);
        acc[fq * 4 + 0] += hw * lv.x;
        acc[fq * 4 + 1] += hw * lv.y;
        acc[fq * 4 + 2] += hw * lv.z;
        acc[fq * 4 + 3] += hw * lv.w;
      }
    }
#pragma unroll
    for (int q = 0; q < 16; ++q) curf[q] = nxtf[q];
  }

  float whv = Wh[l * 65536 + r];
  size_t cbase = (size_t)(nf * 16 + ks) * 1024 + (size_t)h * 256 + (size_t)tid;
#pragma unroll
  for (int t = 0; t < 32; ++t) {
    float w = (acc[t] + whv) * OMEGA_SC;
    _Float16 hi = (_Float16)w;
    _Float16 lo = (_Float16)((w - (float)hi) * LO_SCALE);
    size_t b = (size_t)(t * 3 + l) * 131072 + cbase;
    whblob[b] = hi;
    whblob[b + 512] = lo;
  }
}

// ---------------------------------------------------------------------------
// Kernel B: fused SIREN, REGISTER-RESIDENT x, zero main-loop barriers.
// Each wave owns 32 px end-to-end: x[32px][256k] (hi+lo fp16, packed
// operand-ready f16x8) lives in 256 VGPRs. The k-perm makes each layer's
// C-fragments directly consumable as the next layer's B-fragments (see top).
// Per layer: stream A from L2 (depth-2 per frag-pair), 384 MFMAs, per-pair
// sine+split epilogue into the "next" register file, then register copy.
// 1 wave/SIMD (~430 VGPR), 4 independent waves/CU -> no phase-lock; the
// per-SIMD matrix pipe (32cyc/MFMA) is saturated by a single wave's stream.
// Split-fp16: hh->accA, hl+lh->accB, out = accA + accB/2048.
// ---------------------------------------------------------------------------
__global__ __launch_bounds__(256, 1) void kb_siren(
    const float* __restrict__ coords, const _Float16* __restrict__ whblob,
    const _Float16* __restrict__ w0blob, const float* __restrict__ beff,
    const float* __restrict__ Wf, const float* __restrict__ bf,
    float* __restrict__ out) {
  __shared__ float wf_s[768];
  int tid = threadIdx.x;
  int bid0 = blockIdx.x;
  int bid = (bid0 & 7) * 128 + (bid0 >> 3);  // XCD swizzle: 4 frames per XCD
  int wv = tid >> 6, lane = tid & 63, col = lane & 31, h = lane >> 5;
  int wave_id = bid * 4 + wv;
  int t = wave_id >> 7, tile = wave_id & 127;

  {
    int p = tid;
    int pn = p >> 5, pu = (p >> 4) & 1, ph = (p >> 3) & 1, pj = p & 7;
    int orig = pn * 32 + pu * 16 + 8 * (pj >> 2) + 4 * ph + (pj & 3);
#pragma unroll
    for (int c = 0; c < 3; ++c)
      wf_s[c * 256 + p] = Wf[c * 256 + orig];
  }
  __syncthreads();  // the ONLY block barrier

  // x register files: [frag 0..7][u-half 0..1], current and next layer
  HU4 xch[8][2], xcl[8][2], xnh[8][2], xnl[8][2];

  // layer-0 B built from coords (positions p<16: orig = 8*(j>>2)+4h+(j&3))
  HU4 bch, bcl;
  {
    const float* cp = coords + (size_t)(t * 4096 + tile * 32 + col) * 3;
    float v0 = cp[0], v1 = cp[1], v2 = cp[2];
    if (h) { v0 = 0.f; v1 = 0.f; v2 = 0.f; }
#pragma unroll
    for (int j = 0; j < 8; ++j) { bch.h[j] = (_Float16)0.f; bcl.h[j] = (_Float16)0.f; }
    _Float16 q0 = (_Float16)v0, q1 = (_Float16)v1, q2 = (_Float16)v2;
    bch.h[0] = q0; bch.h[1] = q1; bch.h[2] = q2;
    bcl.h[0] = (_Float16)((v0 - (float)q0) * LO_SCALE);
    bcl.h[1] = (_Float16)((v1 - (float)q1) * LO_SCALE);
    bcl.h[2] = (_Float16)((v2 - (float)q2) * LO_SCALE);
  }

  auto sin2pi = [](float x) {
    float f, r;
    asm("v_fract_f32 %0, %1" : "=v"(f) : "v"(x));
    asm("v_sin_f32 %0, %1" : "=v"(r) : "v"(f));
    return r;
  };

  auto init_bias = [&](int bk, int nf, f32x16& A, f32x16& B) {
    const float* bp = beff + ((t * 4 + bk) << 8) + nf * 32 + h * 4;
#pragma unroll
    for (int rq = 0; rq < 4; ++rq) {
      float4 bv = *(const float4*)(bp + rq * 8);
      float ba[4];
      *(float4*)ba = bv;
#pragma unroll
      for (int q = 0; q < 4; ++q) { A[rq * 4 + q] = ba[q]; B[rq * 4 + q] = 0.f; }
    }
  };

  auto aload = [&](const _Float16* blobL, int idx2, f16x8& ah, f16x8& al) {
    const _Float16* p = blobL + (size_t)idx2 * 512 + lane * 8;
    ah = *(const f16x8*)p;
    al = *(const f16x8*)(p + 512);
  };

  // activation + RTZ split, packed straight into operand-ready f16x8 halves
  auto epi = [&](f32x16& A, f32x16& B, HU4& oh0, HU4& ol0, HU4& oh1, HU4& ol1) {
    float val[16];
#pragma unroll
    for (int r = 0; r < 16; ++r) val[r] = sin2pi(fmaf(B[r], LO_INV, A[r]));
#pragma unroll
    for (int k = 0; k < 4; ++k) {
      h2 hp = __builtin_amdgcn_cvt_pkrtz(val[2 * k], val[2 * k + 1]);
      oh0.p[k] = hp;
      ol0.p[k] = __builtin_amdgcn_cvt_pkrtz((val[2 * k] - (float)hp[0]) * LO_SCALE,
                                            (val[2 * k + 1] - (float)hp[1]) * LO_SCALE);
      h2 hq = __builtin_amdgcn_cvt_pkrtz(val[8 + 2 * k], val[8 + 2 * k + 1]);
      oh1.p[k] = hq;
      ol1.p[k] = __builtin_amdgcn_cvt_pkrtz((val[8 + 2 * k] - (float)hq[0]) * LO_SCALE,
                                            (val[8 + 2 * k + 1] - (float)hq[1]) * LO_SCALE);
    }
  };

  // ---- layer 0 (K=16, frag pairs, depth-2 A prefetch). Writes xch directly.
  {
    const _Float16* w0b = w0blob + (size_t)t * 8192;
    f16x8 Ph[2][2], Pl[2][2];  // [pair parity][frag-in-pair]
    aload(w0b, 0, Ph[0][0], Pl[0][0]);
    aload(w0b, 2, Ph[0][1], Pl[0][1]);
    aload(w0b, 4, Ph[1][0], Pl[1][0]);
    aload(w0b, 6, Ph[1][1], Pl[1][1]);
#pragma unroll
    for (int np = 0; np < 4; ++np) {
      int par = np & 1;
      f32x16 aA0, aB0, aA1, aB1;
      init_bias(0, np * 2, aA0, aB0);
      init_bias(0, np * 2 + 1, aA1, aB1);
      f16x8 a0h = Ph[par][0], a0l = Pl[par][0];
      f16x8 a1h = Ph[par][1], a1l = Pl[par][1];
      if (np + 2 < 4) {
        aload(w0b, (np * 2 + 4) * 2, Ph[par][0], Pl[par][0]);
        aload(w0b, (np * 2 + 5) * 2, Ph[par][1], Pl[par][1]);
      }
      aA0 = __builtin_amdgcn_mfma_f32_32x32x16_f16(a0h, bch.v, aA0, 0, 0, 0);
      aA1 = __builtin_amdgcn_mfma_f32_32x32x16_f16(a1h, bch.v, aA1, 0, 0, 0);
      aB0 = __builtin_amdgcn_mfma_f32_32x32x16_f16(a0h, bcl.v, aB0, 0, 0, 0);
      aB1 = __builtin_amdgcn_mfma_f32_32x32x16_f16(a1h, bcl.v, aB1, 0, 0, 0);
      aB0 = __builtin_amdgcn_mfma_f32_32x32x16_f16(a0l, bch.v, aB0, 0, 0, 0);
      aB1 = __builtin_amdgcn_mfma_f32_32x32x16_f16(a1l, bch.v, aB1, 0, 0, 0);
      epi(aA0, aB0, xch[np * 2][0], xcl[np * 2][0], xch[np * 2][1], xcl[np * 2][1]);
      epi(aA1, aB1, xch[np * 2 + 1][0], xcl[np * 2 + 1][0], xch[np * 2 + 1][1], xcl[np * 2 + 1][1]);
    }
  }

  // ---- hidden layers (runtime loop; x ping-pong via register copy)
#pragma unroll 1
  for (int li = 0; li < 3; ++li) {
    const _Float16* bl = whblob + (size_t)(t * 3 + li) * 131072;
#pragma unroll
    for (int np = 0; np < 4; ++np) {
      int f0 = np * 2, f1 = np * 2 + 1;
      f32x16 aA0, aB0, aA1, aB1;
      init_bias(li + 1, f0, aA0, aB0);
      init_bias(li + 1, f1, aA1, aB1);
      f16x8 S0h[2], S0l[2], S1h[2], S1l[2];  // depth-2 per A-stream
      aload(bl, (f0 * 16 + 0) * 2, S0h[0], S0l[0]);
      aload(bl, (f1 * 16 + 0) * 2, S1h[0], S1l[0]);
      aload(bl, (f0 * 16 + 1) * 2, S0h[1], S0l[1]);
      aload(bl, (f1 * 16 + 1) * 2, S1h[1], S1l[1]);
#pragma unroll
      for (int ks = 0; ks < 16; ++ks) {
        f16x8 a0h = S0h[ks & 1], a0l = S0l[ks & 1];
        f16x8 a1h = S1h[ks & 1], a1l = S1l[ks & 1];
        if (ks + 2 < 16) {
          aload(bl, (f0 * 16 + ks + 2) * 2, S0h[ks & 1], S0l[ks & 1]);
          aload(bl, (f1 * 16 + ks + 2) * 2, S1h[ks & 1], S1l[ks & 1]);
        }
        int q = ks >> 1, s = ks & 1;
        f16x8 bh_ = xch[q][s].v;
        f16x8 bl_ = xcl[q][s].v;
        aA0 = __builtin_amdgcn_mfma_f32_32x32x16_f16(a0h, bh_, aA0, 0, 0, 0);
        aA1 = __builtin_amdgcn_mfma_f32_32x32x16_f16(a1h, bh_, aA1, 0, 0, 0);
        aB0 = __builtin_amdgcn_mfma_f32_32x32x16_f16(a0h, bl_, aB0, 0, 0, 0);
        aB1 = __builtin_amdgcn_mfma_f32_32x32x16_f16(a1h, bl_, aB1, 0, 0, 0);
        aB0 = __builtin_amdgcn_mfma_f32_32x32x16_f16(a0l, bh_, aB0, 0, 0, 0);
        aB1 = __builtin_amdgcn_mfma_f32_32x32x16_f16(a1l, bh_, aB1, 0, 0, 0);
      }
      epi(aA0, aB0, xnh[f0][0], xnl[f0][0], xnh[f0][1], xnl[f0][1]);
      epi(aA1, aB1, xnh[f1][0], xnl[f1][0], xnh[f1][1], xnl[f1][1]);
    }
#pragma unroll
    for (int i2 = 0; i2 < 8; ++i2)
#pragma unroll
      for (int s2 = 0; s2 < 2; ++s2) {
        xch[i2][s2].v = xnh[i2][s2].v;
        xcl[i2][s2].v = xnl[i2][s2].v;
      }
  }

  // ---- final linear: per-lane dot over its 128 positions, shfl-combine
  {
    float pc0 = 0.f, pc1 = 0.f, pc2 = 0.f;
#pragma unroll
    for (int nf = 0; nf < 8; ++nf)
#pragma unroll
      for (int s = 0; s < 2; ++s) {
        const float* wp = wf_s + nf * 32 + s * 16 + h * 8;
        float w0a[8], w1a[8], w2a[8];
        *(float4*)(w0a) = *(const float4*)(wp);
        *(float4*)(w0a + 4) = *(const float4*)(wp + 4);
        *(float4*)(w1a) = *(const float4*)(wp + 256);
        *(float4*)(w1a + 4) = *(const float4*)(wp + 260);
        *(float4*)(w2a) = *(const float4*)(wp + 512);
        *(float4*)(w2a + 4) = *(const float4*)(wp + 516);
#pragma unroll
        for (int j = 0; j < 8; ++j) {
          float xv = (float)xch[nf][s].h[j] + (float)xcl[nf][s].h[j] * LO_INV;
          pc0 += xv * w0a[j];
          pc1 += xv * w1a[j];
          pc2 += xv * w2a[j];
        }
      }
    pc0 += __shfl_xor(pc0, 32, 64);
    pc1 += __shfl_xor(pc1, 32, 64);
    pc2 += __shfl_xor(pc2, 32, 64);
    if (h == 0) {
      size_t o = (size_t)(t * 4096 + tile * 32 + col) * 3;
      out[o + 0] = pc0 + bf[0];
      out[o + 1] = pc1 + bf[1];
      out[o + 2] = pc2 + bf[2];
    }
  }
}

// ---------------------------------------------------------------------------
extern "C" void kernel_launch(void* const* d_in, const int* in_sizes, int n_in,
                              void* d_out, int out_size, void* d_ws, size_t ws_size,
                              hipStream_t stream) {
  const float* coords  = (const float*)d_in[0];
  const float* latents = (const float*)d_in[1];
  const float* W0      = (const float*)d_in[2];
  const float* b0      = (const float*)d_in[3];
  const float* Wh      = (const float*)d_in[4];
  const float* bh      = (const float*)d_in[5];
  const float* Wf      = (const float*)d_in[6];
  const float* bf      = (const float*)d_in[7];
  const float* HW0     = (const float*)d_in[8];
  const float* HWh     = (const float*)d_in[9];
  const float* HB      = (const float*)d_in[10];
  float* outp = (float*)d_out;

  char* w = (char*)d_ws;
  _Float16* whblob = (_Float16*)w;                   // 12,582,912 halves
  _Float16* w0blob = (_Float16*)(w + 25165824);      // 262,144 halves
  float*    beff   = (float*)(w + 25690112);         // 32,768 floats

  kab<<<1024, 256, 0, stream>>>(latents, W0, b0, bh, HW0, HB, Wh, HWh,
                                w0blob, beff, whblob);
  kb_siren<<<1024, 256, 0, stream>>>(coords, whblob, w0blob, beff, Wf, bf, outp);
}